// Round 4
// baseline (244.197 us; speedup 1.0000x reference)
//
#include <hip/hip_runtime.h>
#include <hip/hip_bf16.h>

// RBF network fused kernel for MI355X (gfx950).
// B=131072, D=64, H=512, O=16.
// Grid: 1024 blocks x 256 threads (4 waves). Each block: 128 rows in 8 subtiles of 16.
// Wave w owns h-slice [w*128, (w+1)*128): centroid/weight fragments held in VGPRs.
// R4 changes vs R3: (a) software-pipelined x staging (prefetch next tile into regs
// during compute, double-buffered x_lds), (b) 2 barriers per M-tile instead of 3,
// (c) hid tile XOR-swizzled ((row>>2)<<5 on byte addr) -> conflict-free b16 stores
// and floor-optimal b128 reads, (d) part padded to stride 20 (aligned b128 stores,
// ~2-way reads), (e) __launch_bounds__(256,4) to keep 4 blocks/CU resident.

#define NDIM 64
#define NHID 512
#define NOUT 16

typedef __attribute__((ext_vector_type(8))) short bf16x8;  // 8 bf16 in 4 VGPRs
typedef __attribute__((ext_vector_type(4))) float f32x4;

#if __has_builtin(__builtin_amdgcn_exp2f)
#define EXP2F(x) __builtin_amdgcn_exp2f(x)
#else
#define EXP2F(x) exp2f(x)
#endif

// fp32 -> bf16 round-to-nearest-even (finite inputs only here)
static __device__ __forceinline__ short f2bf(float f) {
    unsigned int u = __float_as_uint(f);
    unsigned int r = (u + 0x7FFFu + ((u >> 16) & 1u)) >> 16;
    return (short)r;
}

__global__ __launch_bounds__(256, 4)
void rbf_fused(const float* __restrict__ x, const float* __restrict__ cen,
               const float* __restrict__ sig, const float* __restrict__ wgt,
               const float* __restrict__ bias, float* __restrict__ out)
{
    // x_lds: double-buffered 16-row bf16 tile (stride 72 shorts).
    // hid: per-wave 16x128 bf16, XOR-swizzled, stride 128 shorts (no pad needed).
    // part: per-wave 16(o) x 20(m-padded) f32 partials.
    __shared__ __align__(16) short x_lds[2][16][72];
    __shared__ __align__(16) float xsq_lds[2][16];
    __shared__ __align__(16) short hid[4][16 * 128];
    __shared__ __align__(16) float part[4][16][20];

    const int tid  = threadIdx.x;
    const int w    = tid >> 6;    // wave 0..3
    const int lane = tid & 63;
    const int g    = lane >> 4;   // 16-lane group 0..3
    const int c    = lane & 15;
    const int hbase = w * 128;

    // ---- per-block preload: centroid B-frags + per-h coefficients ----
    bf16x8 b1[8][2];
    float A2c[8], AHc[8], NBc[8];
#pragma unroll
    for (int nt = 0; nt < 8; ++nt) {
        const int h = hbase + nt * 16 + c;
        const float* cr = cen + (long)h * NDIM + g * 8;
        float csq = 0.f;
        bf16x8 fr0, fr1;
        {
            f32x4 v0 = *(const f32x4*)(cr);
            f32x4 v1 = *(const f32x4*)(cr + 4);
            csq += v0[0]*v0[0] + v0[1]*v0[1] + v0[2]*v0[2] + v0[3]*v0[3];
            csq += v1[0]*v1[0] + v1[1]*v1[1] + v1[2]*v1[2] + v1[3]*v1[3];
            fr0[0]=f2bf(v0[0]); fr0[1]=f2bf(v0[1]); fr0[2]=f2bf(v0[2]); fr0[3]=f2bf(v0[3]);
            fr0[4]=f2bf(v1[0]); fr0[5]=f2bf(v1[1]); fr0[6]=f2bf(v1[2]); fr0[7]=f2bf(v1[3]);
        }
        {
            f32x4 v0 = *(const f32x4*)(cr + 32);
            f32x4 v1 = *(const f32x4*)(cr + 36);
            csq += v0[0]*v0[0] + v0[1]*v0[1] + v0[2]*v0[2] + v0[3]*v0[3];
            csq += v1[0]*v1[0] + v1[1]*v1[1] + v1[2]*v1[2] + v1[3]*v1[3];
            fr1[0]=f2bf(v0[0]); fr1[1]=f2bf(v0[1]); fr1[2]=f2bf(v0[2]); fr1[3]=f2bf(v0[3]);
            fr1[4]=f2bf(v1[0]); fr1[5]=f2bf(v1[1]); fr1[6]=f2bf(v1[2]); fr1[7]=f2bf(v1[3]);
        }
        b1[nt][0] = fr0; b1[nt][1] = fr1;
        csq += __shfl_xor(csq, 16);   // lanes differing in bits 4,5 hold disjoint k-chunks
        csq += __shfl_xor(csq, 32);
        float s = sig[h];
        float a = 1.4426950408889634f / (2.0f * s * s);   // log2(e)/(2 sigma^2)
        a = fminf(a, 1e30f);
        A2c[nt] = 2.0f * a;
        AHc[nt] = a;
        NBc[nt] = -a * csq;
    }

    // ---- weight B-frags: B[k][o] = W[hbase + ks*32 + g*8 + j][c] ----
    bf16x8 w2[4];
#pragma unroll
    for (int ks = 0; ks < 4; ++ks) {
        bf16x8 f;
#pragma unroll
        for (int j = 0; j < 8; ++j) {
            f[j] = f2bf(wgt[(hbase + ks * 32 + g * 8 + j) * NOUT + c]);
        }
        w2[ks] = f;
    }
    const float biasv = bias[c];

    const long rowblock = (long)blockIdx.x * 128;
    const int r  = tid >> 4;    // staging/epilogue row 0..15
    const int cc = tid & 15;    // staging col group / epilogue o
    const float* xp = x + (rowblock + r) * NDIM + cc * 4;
    float* outp = out + rowblock * NOUT;
    short* hid_w = hid[w];

    // ---- prologue: stage tile 0 ----
    {
        f32x4 v = *(const f32x4*)xp;
        float sq = v[0]*v[0] + v[1]*v[1] + v[2]*v[2] + v[3]*v[3];
        sq += __shfl_xor(sq, 1);
        sq += __shfl_xor(sq, 2);
        sq += __shfl_xor(sq, 4);
        sq += __shfl_xor(sq, 8);
        short4 s4;
        s4.x = f2bf(v[0]); s4.y = f2bf(v[1]); s4.z = f2bf(v[2]); s4.w = f2bf(v[3]);
        *(short4*)&x_lds[0][r][cc * 4] = s4;
        if (cc == 0) xsq_lds[0][r] = sq;
    }

    for (int ms = 0; ms < 8; ++ms) {
        const int cur = ms & 1;

        // issue prefetch for tile ms+1 (latency hidden under this tile's compute)
        f32x4 vnext;
        if (ms < 7) vnext = *(const f32x4*)(xp + (ms + 1) * 16 * NDIM);

        __syncthreads();   // (1) x_lds[cur]/xsq[cur] staged by all; prev part consumed

        bf16x8 af0 = *(const bf16x8*)&x_lds[cur][c][g * 8];
        bf16x8 af1 = *(const bf16x8*)&x_lds[cur][c][32 + g * 8];
        f32x4 xs4 = *(const f32x4*)&xsq_lds[cur][4 * g];

        // GEMM1 + RBF activation -> swizzled hid tile (wave-private, no barrier)
#pragma unroll
        for (int nt = 0; nt < 8; ++nt) {
            f32x4 acc = {0.f, 0.f, 0.f, 0.f};
            acc = __builtin_amdgcn_mfma_f32_16x16x32_bf16(af0, b1[nt][0], acc, 0, 0, 0);
            acc = __builtin_amdgcn_mfma_f32_16x16x32_bf16(af1, b1[nt][1], acc, 0, 0, 0);
#pragma unroll
            for (int rr = 0; rr < 4; ++rr) {
                float nbx = fmaf(-AHc[nt], xs4[rr], NBc[nt]);
                float arg = fmaf(A2c[nt], acc[rr], nbx);
                // row = 4g+rr, col = nt*16+c; byte ^= (row>>2)<<5  (== g<<5)
                int byte = ((4 * g + rr) << 8) + ((nt * 16 + c) << 1);
                byte ^= (g << 5);
                hid_w[byte >> 1] = f2bf(EXP2F(arg));
            }
        }

        // GEMM2 over this wave's K-slice of 128 (same-wave LDS, waitcnt-ordered)
        f32x4 acc2 = {0.f, 0.f, 0.f, 0.f};
#pragma unroll
        for (int ks = 0; ks < 4; ++ks) {
            int byte = (c << 8) + ((ks * 32 + g * 8) << 1);
            byte ^= ((c >> 2) << 5);
            bf16x8 a2 = *(const bf16x8*)&hid_w[byte >> 1];
            acc2 = __builtin_amdgcn_mfma_f32_16x16x32_bf16(a2, w2[ks], acc2, 0, 0, 0);
        }
        // C layout: row m = 4g+rr, col o = c. Store transposed [o][m] -> b128.
        *(f32x4*)&part[w][c][4 * g] = acc2;

        // write prefetched tile to the other x buffer (before barrier 2)
        if (ms < 7) {
            float sq = vnext[0]*vnext[0] + vnext[1]*vnext[1]
                     + vnext[2]*vnext[2] + vnext[3]*vnext[3];
            sq += __shfl_xor(sq, 1);
            sq += __shfl_xor(sq, 2);
            sq += __shfl_xor(sq, 4);
            sq += __shfl_xor(sq, 8);
            short4 s4;
            s4.x = f2bf(vnext[0]); s4.y = f2bf(vnext[1]);
            s4.z = f2bf(vnext[2]); s4.w = f2bf(vnext[3]);
            *(short4*)&x_lds[cur ^ 1][r][cc * 4] = s4;
            if (cc == 0) xsq_lds[cur ^ 1][r] = sq;
        }

        __syncthreads();   // (2) part written by all waves; next x tile staged

        // epilogue: thread (m=r, o=cc): sum wave partials + bias, normalize
        {
            float v = biasv + part[0][cc][r] + part[1][cc][r]
                            + part[2][cc][r] + part[3][cc][r];
            float s = v;
            s += __shfl_xor(s, 1);
            s += __shfl_xor(s, 2);
            s += __shfl_xor(s, 4);
            s += __shfl_xor(s, 8);
            outp[ms * 16 * NOUT + r * NOUT + cc] = v / s;
        }
    }
}

extern "C" void kernel_launch(void* const* d_in, const int* in_sizes, int n_in,
                              void* d_out, int out_size, void* d_ws, size_t ws_size,
                              hipStream_t stream) {
    const float* x    = (const float*)d_in[0];
    const float* cen  = (const float*)d_in[1];
    const float* sig  = (const float*)d_in[2];
    const float* wgt  = (const float*)d_in[3];
    const float* bias = (const float*)d_in[4];
    float* out = (float*)d_out;
    (void)in_sizes; (void)n_in; (void)d_ws; (void)ws_size; (void)out_size;

    rbf_fused<<<dim3(1024), dim3(256), 0, stream>>>(x, cen, sig, wgt, bias, out);
}

// Round 8
// 116.091 us; speedup vs baseline: 2.1035x; 2.1035x over previous
//
#include <hip/hip_runtime.h>
#include <hip/hip_bf16.h>

// RBF network fused kernel for MI355X (gfx950).
// B=131072, D=64, H=512, O=16.
// Grid: 1024 blocks x 256 threads (4 waves). Each block: 128 rows in 8 subtiles of 16.
// Wave w owns h-slice [w*128, (w+1)*128): centroid/weight fragments held in VGPRs.
// R5 vs R4: launch_bounds back to (256,2) — (256,4) forced a 64-VGPR cap and
// catastrophic scratch spill (FETCH 17->284MB). hid layout reverted to R3's
// plain padded [16][136] (R4's XOR swizzle made GEMM2 reads ~4-way conflicted).
// Keeps: prefetch pipeline, 2 barriers/tile, part[16][20] padding.

#define NDIM 64
#define NHID 512
#define NOUT 16

typedef __attribute__((ext_vector_type(8))) short bf16x8;  // 8 bf16 in 4 VGPRs
typedef __attribute__((ext_vector_type(4))) float f32x4;

#if __has_builtin(__builtin_amdgcn_exp2f)
#define EXP2F(x) __builtin_amdgcn_exp2f(x)
#else
#define EXP2F(x) exp2f(x)
#endif

// fp32 -> bf16 round-to-nearest-even (finite inputs only here)
static __device__ __forceinline__ short f2bf(float f) {
    unsigned int u = __float_as_uint(f);
    unsigned int r = (u + 0x7FFFu + ((u >> 16) & 1u)) >> 16;
    return (short)r;
}

__global__ __launch_bounds__(256, 2)
void rbf_fused(const float* __restrict__ x, const float* __restrict__ cen,
               const float* __restrict__ sig, const float* __restrict__ wgt,
               const float* __restrict__ bias, float* __restrict__ out)
{
    // x_lds: double-buffered 16-row bf16 tile (stride 72 shorts).
    // hid: per-wave 16x128 bf16 tile, padded stride 136 (reads ~free, stores ~2-way).
    // part: per-wave 16(o) x 20(m-padded) f32 partials.
    __shared__ __align__(16) short x_lds[2][16][72];
    __shared__ __align__(16) float xsq_lds[2][16];
    __shared__ __align__(16) short hid[4][16][136];
    __shared__ __align__(16) float part[4][16][20];

    const int tid  = threadIdx.x;
    const int w    = tid >> 6;    // wave 0..3
    const int lane = tid & 63;
    const int g    = lane >> 4;   // 16-lane group 0..3
    const int c    = lane & 15;
    const int hbase = w * 128;

    // ---- per-block preload: centroid B-frags + per-h coefficients ----
    bf16x8 b1[8][2];
    float A2c[8], AHc[8], NBc[8];
#pragma unroll
    for (int nt = 0; nt < 8; ++nt) {
        const int h = hbase + nt * 16 + c;
        const float* cr = cen + (long)h * NDIM + g * 8;
        float csq = 0.f;
        bf16x8 fr0, fr1;
        {
            f32x4 v0 = *(const f32x4*)(cr);
            f32x4 v1 = *(const f32x4*)(cr + 4);
            csq += v0[0]*v0[0] + v0[1]*v0[1] + v0[2]*v0[2] + v0[3]*v0[3];
            csq += v1[0]*v1[0] + v1[1]*v1[1] + v1[2]*v1[2] + v1[3]*v1[3];
            fr0[0]=f2bf(v0[0]); fr0[1]=f2bf(v0[1]); fr0[2]=f2bf(v0[2]); fr0[3]=f2bf(v0[3]);
            fr0[4]=f2bf(v1[0]); fr0[5]=f2bf(v1[1]); fr0[6]=f2bf(v1[2]); fr0[7]=f2bf(v1[3]);
        }
        {
            f32x4 v0 = *(const f32x4*)(cr + 32);
            f32x4 v1 = *(const f32x4*)(cr + 36);
            csq += v0[0]*v0[0] + v0[1]*v0[1] + v0[2]*v0[2] + v0[3]*v0[3];
            csq += v1[0]*v1[0] + v1[1]*v1[1] + v1[2]*v1[2] + v1[3]*v1[3];
            fr1[0]=f2bf(v0[0]); fr1[1]=f2bf(v0[1]); fr1[2]=f2bf(v0[2]); fr1[3]=f2bf(v0[3]);
            fr1[4]=f2bf(v1[0]); fr1[5]=f2bf(v1[1]); fr1[6]=f2bf(v1[2]); fr1[7]=f2bf(v1[3]);
        }
        b1[nt][0] = fr0; b1[nt][1] = fr1;
        csq += __shfl_xor(csq, 16);   // lanes differing in bits 4,5 hold disjoint k-chunks
        csq += __shfl_xor(csq, 32);
        float s = sig[h];
        float a = 1.4426950408889634f / (2.0f * s * s);   // log2(e)/(2 sigma^2)
        a = fminf(a, 1e30f);
        A2c[nt] = 2.0f * a;
        AHc[nt] = a;
        NBc[nt] = -a * csq;
    }

    // ---- weight B-frags: B[k][o] = W[hbase + ks*32 + g*8 + j][c] ----
    bf16x8 w2[4];
#pragma unroll
    for (int ks = 0; ks < 4; ++ks) {
        bf16x8 f;
#pragma unroll
        for (int j = 0; j < 8; ++j) {
            f[j] = f2bf(wgt[(hbase + ks * 32 + g * 8 + j) * NOUT + c]);
        }
        w2[ks] = f;
    }
    const float biasv = bias[c];

    const long rowblock = (long)blockIdx.x * 128;
    const int r  = tid >> 4;    // staging/epilogue row 0..15
    const int cc = tid & 15;    // staging col group / epilogue o
    const float* xp = x + (rowblock + r) * NDIM + cc * 4;
    float* outp = out + rowblock * NOUT;

    // ---- prologue: stage tile 0 ----
    {
        f32x4 v = *(const f32x4*)xp;
        float sq = v[0]*v[0] + v[1]*v[1] + v[2]*v[2] + v[3]*v[3];
        sq += __shfl_xor(sq, 1);
        sq += __shfl_xor(sq, 2);
        sq += __shfl_xor(sq, 4);
        sq += __shfl_xor(sq, 8);
        short4 s4;
        s4.x = f2bf(v[0]); s4.y = f2bf(v[1]); s4.z = f2bf(v[2]); s4.w = f2bf(v[3]);
        *(short4*)&x_lds[0][r][cc * 4] = s4;
        if (cc == 0) xsq_lds[0][r] = sq;
    }

    for (int ms = 0; ms < 8; ++ms) {
        const int cur = ms & 1;

        // issue prefetch for tile ms+1 (latency hidden under this tile's compute)
        f32x4 vnext;
        if (ms < 7) vnext = *(const f32x4*)(xp + (ms + 1) * 16 * NDIM);

        __syncthreads();   // (1) x_lds[cur]/xsq[cur] staged by all; prev part consumed

        bf16x8 af0 = *(const bf16x8*)&x_lds[cur][c][g * 8];
        bf16x8 af1 = *(const bf16x8*)&x_lds[cur][c][32 + g * 8];
        f32x4 xs4 = *(const f32x4*)&xsq_lds[cur][4 * g];

        // GEMM1 + RBF activation -> hid tile (wave-private, same-wave ordering only)
#pragma unroll
        for (int nt = 0; nt < 8; ++nt) {
            f32x4 acc = {0.f, 0.f, 0.f, 0.f};
            acc = __builtin_amdgcn_mfma_f32_16x16x32_bf16(af0, b1[nt][0], acc, 0, 0, 0);
            acc = __builtin_amdgcn_mfma_f32_16x16x32_bf16(af1, b1[nt][1], acc, 0, 0, 0);
#pragma unroll
            for (int rr = 0; rr < 4; ++rr) {
                float nbx = fmaf(-AHc[nt], xs4[rr], NBc[nt]);
                float arg = fmaf(A2c[nt], acc[rr], nbx);
                hid[w][4 * g + rr][nt * 16 + c] = f2bf(EXP2F(arg));
            }
        }

        // GEMM2 over this wave's K-slice of 128 (same-wave LDS, waitcnt-ordered)
        f32x4 acc2 = {0.f, 0.f, 0.f, 0.f};
#pragma unroll
        for (int ks = 0; ks < 4; ++ks) {
            bf16x8 a2 = *(const bf16x8*)&hid[w][c][ks * 32 + g * 8];
            acc2 = __builtin_amdgcn_mfma_f32_16x16x32_bf16(a2, w2[ks], acc2, 0, 0, 0);
        }
        // C layout: row m = 4g+rr, col o = c. Store transposed [o][m] -> b128.
        *(f32x4*)&part[w][c][4 * g] = acc2;

        // write prefetched tile to the other x buffer (before barrier 2)
        if (ms < 7) {
            float sq = vnext[0]*vnext[0] + vnext[1]*vnext[1]
                     + vnext[2]*vnext[2] + vnext[3]*vnext[3];
            sq += __shfl_xor(sq, 1);
            sq += __shfl_xor(sq, 2);
            sq += __shfl_xor(sq, 4);
            sq += __shfl_xor(sq, 8);
            short4 s4;
            s4.x = f2bf(vnext[0]); s4.y = f2bf(vnext[1]);
            s4.z = f2bf(vnext[2]); s4.w = f2bf(vnext[3]);
            *(short4*)&x_lds[cur ^ 1][r][cc * 4] = s4;
            if (cc == 0) xsq_lds[cur ^ 1][r] = sq;
        }

        __syncthreads();   // (2) part written by all waves; next x tile staged

        // epilogue: thread (m=r, o=cc): sum wave partials + bias, normalize
        {
            float v = biasv + part[0][cc][r] + part[1][cc][r]
                            + part[2][cc][r] + part[3][cc][r];
            float s = v;
            s += __shfl_xor(s, 1);
            s += __shfl_xor(s, 2);
            s += __shfl_xor(s, 4);
            s += __shfl_xor(s, 8);
            outp[ms * 16 * NOUT + r * NOUT + cc] = v / s;
        }
    }
}

extern "C" void kernel_launch(void* const* d_in, const int* in_sizes, int n_in,
                              void* d_out, int out_size, void* d_ws, size_t ws_size,
                              hipStream_t stream) {
    const float* x    = (const float*)d_in[0];
    const float* cen  = (const float*)d_in[1];
    const float* sig  = (const float*)d_in[2];
    const float* wgt  = (const float*)d_in[3];
    const float* bias = (const float*)d_in[4];
    float* out = (float*)d_out;
    (void)in_sizes; (void)n_in; (void)d_ws; (void)ws_size; (void)out_size;

    rbf_fused<<<dim3(1024), dim3(256), 0, stream>>>(x, cen, sig, wgt, bias, out);
}

// Round 11
// 102.618 us; speedup vs baseline: 2.3797x; 1.1313x over previous
//
#include <hip/hip_runtime.h>
#include <hip/hip_bf16.h>

// RBF network, MI355X (gfx950). B=131072, D=64, H=512, O=16.
// R9: fully wave-independent main kernel (ZERO barriers, no cross-wave coupling).
//   prep kernel: centroid -> bf16 MFMA-fragment order (64KB), weight -> bf16
//   fragment order (16KB), coef (a, -a*csq) (4KB), all in d_ws (86KB).
//   main kernel: 1024 blocks x 256; each wave owns 32 rows x all 512 h.
//   Per 2-nt chunk: B-frags from L2-resident ws, 4 MFMA GEMM1, 8 exp2,
//   wave-private hid LDS round-trip (double-buffered), 2 MFMA GEMM2 (K=512
//   accumulated in regs). Epilogue in registers: bias + shfl row-sum + store.
// R5 post-mortem: 46us with all pipes <40% -> barrier/serial-chain bound;
// this removes every __syncthreads from the hot path.

#define NDIM 64
#define NHID 512
#define NOUT 16
#define LOG2E 1.4426950408889634f

typedef __attribute__((ext_vector_type(8))) short bf16x8;  // 8 bf16 in 4 VGPRs
typedef __attribute__((ext_vector_type(4))) float f32x4;
typedef __attribute__((ext_vector_type(2))) float f32x2;

#if __has_builtin(__builtin_amdgcn_exp2f)
#define EXP2F(x) __builtin_amdgcn_exp2f(x)
#else
#define EXP2F(x) exp2f(x)
#endif

// fp32 -> bf16 round-to-nearest-even
static __device__ __forceinline__ short f2bf(float f) {
    unsigned int u = __float_as_uint(f);
    unsigned int r = (u + 0x7FFFu + ((u >> 16) & 1u)) >> 16;
    return (short)r;
}

// d_ws layout (bytes)
#define WS_CFRAG 0          // 64 KB: bf16 centroid frags: [(nt*2+kc)*64 + lane]*16B
#define WS_WFRAG 65536      // 16 KB: bf16 weight frags:  [ks*64 + lane]*16B
#define WS_COF   81920      //  4 KB: float2 (a, -a*csq) per h

// prep: 528 blocks x 64 threads.
// blocks [0,512): centroid row h -> bf16 frag scatter + coef.
// blocks [512,528): weight frag ks.
__global__ __launch_bounds__(64)
void rbf_prep(const float* __restrict__ cen, const float* __restrict__ sig,
              const float* __restrict__ wgt, char* __restrict__ ws)
{
    const int blk = blockIdx.x;
    const int d = threadIdx.x;
    if (blk < NHID) {
        const int h = blk;
        const float v = cen[h * NDIM + d];
        float sq = v * v;
        sq += __shfl_xor(sq, 1);
        sq += __shfl_xor(sq, 2);
        sq += __shfl_xor(sq, 4);
        sq += __shfl_xor(sq, 8);
        sq += __shfl_xor(sq, 16);
        sq += __shfl_xor(sq, 32);
        if (d == 0) {
            float s = sig[h];
            float a = LOG2E / (2.0f * s * s);
            a = fminf(a, 1e30f);                 // sigma==0 guard
            f32x2 cf; cf[0] = a; cf[1] = -a * sq;
            *(f32x2*)(ws + WS_COF + h * 8) = cf;
        }
        // frag position: nt=h>>4, cp=h&15, kc=d>>5, g=(d>>3)&3, j=d&7
        const int nt = h >> 4, cp = h & 15, kc = d >> 5, g = (d >> 3) & 3, j = d & 7;
        const int byte = (((nt * 2 + kc) * 64) + g * 16 + cp) * 16 + j * 2;
        *(short*)(ws + WS_CFRAG + byte) = f2bf(v);
    } else {
        const int ks = blk - NHID;               // 0..15
        const int g = d >> 4, c = d & 15;
        bf16x8 f;
#pragma unroll
        for (int j = 0; j < 8; ++j)
            f[j] = f2bf(wgt[(ks * 32 + g * 8 + j) * NOUT + c]);
        *(bf16x8*)(ws + WS_WFRAG + (ks * 64 + d) * 16) = f;
    }
}

__global__ __launch_bounds__(256, 2)
void rbf_main(const float* __restrict__ x, const float* __restrict__ bias,
              const char* __restrict__ ws, float* __restrict__ out)
{
    // wave-private hid chunk, double-buffered: [wave][buf][m 0..31][kk 0..31 pad 40]
    // row stride 40 shorts = 80B -> 16B-aligned b128 reads at g*8.
    __shared__ __align__(16) short hidb[4][2][32][40];

    const int tid  = threadIdx.x;
    const int w    = tid >> 6;
    const int lane = tid & 63;
    const int g    = lane >> 4;
    const int c    = lane & 15;
    const long r0  = (long)blockIdx.x * 128 + w * 32;

    const bf16x8* cfrag = (const bf16x8*)(ws + WS_CFRAG);
    const bf16x8* wfrag = (const bf16x8*)(ws + WS_WFRAG);
    const char*   cofp  = ws + WS_COF;

    // ---- x A-frags (bf16) + xsq per C-row ----
    bf16x8 A[2][2];
    float xs4[2][4];
#pragma unroll
    for (int mg = 0; mg < 2; ++mg) {
        const float* xr = x + (r0 + mg * 16 + c) * NDIM;
        float sqs = 0.f;
#pragma unroll
        for (int kc = 0; kc < 2; ++kc) {
            f32x4 v0 = *(const f32x4*)(xr + kc * 32 + g * 8);
            f32x4 v1 = *(const f32x4*)(xr + kc * 32 + g * 8 + 4);
            sqs += v0[0]*v0[0] + v0[1]*v0[1] + v0[2]*v0[2] + v0[3]*v0[3];
            sqs += v1[0]*v1[0] + v1[1]*v1[1] + v1[2]*v1[2] + v1[3]*v1[3];
            bf16x8 f;
            f[0]=f2bf(v0[0]); f[1]=f2bf(v0[1]); f[2]=f2bf(v0[2]); f[3]=f2bf(v0[3]);
            f[4]=f2bf(v1[0]); f[5]=f2bf(v1[1]); f[6]=f2bf(v1[2]); f[7]=f2bf(v1[3]);
            A[mg][kc] = f;
        }
        sqs += __shfl_xor(sqs, 16);   // combine the 4 g-chunks of row (mg, c)
        sqs += __shfl_xor(sqs, 32);
#pragma unroll
        for (int rr = 0; rr < 4; ++rr)
            xs4[mg][rr] = __shfl(sqs, 4 * g + rr);   // xsq of C-layout row 4g+rr
    }

    // ---- main loop: 16 K-chunks of 32 h, zero barriers ----
    f32x4 acc2[2] = {{0.f,0.f,0.f,0.f},{0.f,0.f,0.f,0.f}};
#pragma unroll
    for (int ks = 0; ks < 16; ++ks) {
#pragma unroll
        for (int t = 0; t < 2; ++t) {
            const int nt = 2 * ks + t;
            const f32x2 cf = *(const f32x2*)(cofp + (nt * 16 + c) * 8);
            const float a = cf[0], nb = cf[1];
            const float A2 = a + a;
            const bf16x8 b0 = cfrag[(nt * 2 + 0) * 64 + lane];
            const bf16x8 b1 = cfrag[(nt * 2 + 1) * 64 + lane];
#pragma unroll
            for (int mg = 0; mg < 2; ++mg) {
                f32x4 z = {0.f, 0.f, 0.f, 0.f};
                f32x4 acc = __builtin_amdgcn_mfma_f32_16x16x32_bf16(A[mg][0], b0, z, 0, 0, 0);
                acc = __builtin_amdgcn_mfma_f32_16x16x32_bf16(A[mg][1], b1, acc, 0, 0, 0);
#pragma unroll
                for (int rr = 0; rr < 4; ++rr) {
                    float nbx = fmaf(-a, xs4[mg][rr], nb);
                    float arg = fmaf(A2, acc[rr], nbx);
                    hidb[w][ks & 1][mg * 16 + 4 * g + rr][t * 16 + c] = f2bf(EXP2F(arg));
                }
            }
        }
        // GEMM2 for this 32-h chunk (same-wave LDS ordering; no barrier needed)
        const bf16x8 wf  = wfrag[ks * 64 + lane];
        const bf16x8 a20 = *(const bf16x8*)&hidb[w][ks & 1][c][g * 8];
        const bf16x8 a21 = *(const bf16x8*)&hidb[w][ks & 1][c + 16][g * 8];
        acc2[0] = __builtin_amdgcn_mfma_f32_16x16x32_bf16(a20, wf, acc2[0], 0, 0, 0);
        acc2[1] = __builtin_amdgcn_mfma_f32_16x16x32_bf16(a21, wf, acc2[1], 0, 0, 0);
    }

    // ---- epilogue in registers: bias, row-sum over o (c-lanes), normalize ----
    const float bv = bias[c];
#pragma unroll
    for (int mg = 0; mg < 2; ++mg) {
        f32x4 v, s;
#pragma unroll
        for (int rr = 0; rr < 4; ++rr) { v[rr] = acc2[mg][rr] + bv; s[rr] = v[rr]; }
#pragma unroll
        for (int off = 1; off <= 8; off <<= 1) {
#pragma unroll
            for (int rr = 0; rr < 4; ++rr) s[rr] += __shfl_xor(s[rr], off);
        }
#pragma unroll
        for (int rr = 0; rr < 4; ++rr)
            out[(r0 + mg * 16 + 4 * g + rr) * NOUT + c] = v[rr] / s[rr];
    }
}

extern "C" void kernel_launch(void* const* d_in, const int* in_sizes, int n_in,
                              void* d_out, int out_size, void* d_ws, size_t ws_size,
                              hipStream_t stream) {
    const float* x    = (const float*)d_in[0];
    const float* cen  = (const float*)d_in[1];
    const float* sig  = (const float*)d_in[2];
    const float* wgt  = (const float*)d_in[3];
    const float* bias = (const float*)d_in[4];
    float* out = (float*)d_out;
    (void)in_sizes; (void)n_in; (void)ws_size; (void)out_size;

    char* ws = (char*)d_ws;
    rbf_prep<<<dim3(NHID + 16), dim3(64), 0, stream>>>(cen, sig, wgt, ws);
    rbf_main<<<dim3(1024), dim3(256), 0, stream>>>(x, bias, ws, out);
}